// Round 9
// baseline (982.836 us; speedup 1.0000x reference)
//
#include <hip/hip_runtime.h>
#include <hip/hip_fp16.h>
#include <math.h>

#define FDIM   64
#define NB     16      // nodes per block in pre_gemm
#define BSHIFT 6       // bucket = 64 nodes
#define BMASK  63
#define EPTA   8       // edges per thread in binA
#define CHUNKA (EPTA * 256)   // 2048
#define SCH    1024    // scan chunk
#define DMASK  0xFFFFF // dst fits in 20 bits
#define NBKTMX 2048    // max coarse buckets (N/64 = 1563)

// ---------- binA count + minmax partial + zero colsum (one edge sweep) ----------
__global__ __launch_bounds__(256) void count_mm_k(const int* __restrict__ src,
                                                  const float* __restrict__ amount,
                                                  const float* __restrict__ count,
                                                  int* __restrict__ mat,
                                                  float4* __restrict__ partial,
                                                  double* __restrict__ colsum,
                                                  int E, int nblkA, int nbkt) {
  __shared__ int lhist[NBKTMX];
  __shared__ float4 lred[4];
  for (int k = threadIdx.x; k < nbkt; k += 256) lhist[k] = 0;
  if (blockIdx.x == 0)
    for (int i = threadIdx.x; i < 1024; i += 256) colsum[i] = 0.0;
  __syncthreads();
  float amin = 3.4e38f, amax = -3.4e38f, cmin = 3.4e38f, cmax = -3.4e38f;
  int e0 = blockIdx.x * CHUNKA + threadIdx.x * EPTA;
  if (e0 + EPTA <= E) {
    #pragma unroll
    for (int q = 0; q < EPTA; q += 4) {
      int4   s4 = *(const int4*)(src + e0 + q);
      float4 a4 = *(const float4*)(amount + e0 + q);
      float4 c4 = *(const float4*)(count + e0 + q);
      atomicAdd(&lhist[s4.x >> BSHIFT], 1);
      atomicAdd(&lhist[s4.y >> BSHIFT], 1);
      atomicAdd(&lhist[s4.z >> BSHIFT], 1);
      atomicAdd(&lhist[s4.w >> BSHIFT], 1);
      amin = fminf(amin, fminf(fminf(a4.x, a4.y), fminf(a4.z, a4.w)));
      amax = fmaxf(amax, fmaxf(fmaxf(a4.x, a4.y), fmaxf(a4.z, a4.w)));
      cmin = fminf(cmin, fminf(fminf(c4.x, c4.y), fminf(c4.z, c4.w)));
      cmax = fmaxf(cmax, fmaxf(fmaxf(c4.x, c4.y), fmaxf(c4.z, c4.w)));
    }
  } else {
    for (int e = e0; e < E; e++) {
      atomicAdd(&lhist[src[e] >> BSHIFT], 1);
      float a = amount[e], c = count[e];
      amin = fminf(amin, a); amax = fmaxf(amax, a);
      cmin = fminf(cmin, c); cmax = fmaxf(cmax, c);
    }
  }
  #pragma unroll
  for (int off = 32; off; off >>= 1) {
    amin = fminf(amin, __shfl_down(amin, off));
    amax = fmaxf(amax, __shfl_down(amax, off));
    cmin = fminf(cmin, __shfl_down(cmin, off));
    cmax = fmaxf(cmax, __shfl_down(cmax, off));
  }
  if ((threadIdx.x & 63) == 0) lred[threadIdx.x >> 6] = make_float4(amin, amax, cmin, cmax);
  __syncthreads();
  for (int k = threadIdx.x; k < nbkt; k += 256)
    mat[(size_t)k * nblkA + blockIdx.x] = lhist[k];
  if (threadIdx.x == 0) {
    float4 r = lred[0];
    #pragma unroll
    for (int w = 1; w < 4; w++) {
      r.x = fminf(r.x, lred[w].x); r.y = fmaxf(r.y, lred[w].y);
      r.z = fminf(r.z, lred[w].z); r.w = fmaxf(r.w, lred[w].w);
    }
    partial[blockIdx.x] = r;
  }
}

// ---------- scan stage 1: per-chunk sums ----------
__global__ __launch_bounds__(256) void scan1_k(const int* __restrict__ v,
                                               int* __restrict__ bsum, int M) {
  __shared__ int lds[256];
  int t = threadIdx.x, b = blockIdx.x;
  int s = 0;
  for (int i = b * SCH + t; i < min((b + 1) * SCH, M); i += 256) s += v[i];
  lds[t] = s; __syncthreads();
  for (int off = 128; off; off >>= 1) {
    if (t < off) lds[t] += lds[t + off];
    __syncthreads();
  }
  if (t == 0) bsum[b] = lds[0];
}

// ---------- scan stage 2 + minmax final reduce (1 block) ----------
__global__ __launch_bounds__(256) void scan2_k(const int* __restrict__ bsum,
                                               int* __restrict__ bexcl, int nchunk,
                                               const float4* __restrict__ partial,
                                               float* __restrict__ mmf, int nb) {
  __shared__ int lds[256];
  int t = threadIdx.x;
  int running = 0;
  for (int c0 = 0; c0 < nchunk; c0 += 256) {
    int x = (c0 + t < nchunk) ? bsum[c0 + t] : 0;
    lds[t] = x; __syncthreads();
    for (int off = 1; off < 256; off <<= 1) {
      int v = (t >= off) ? lds[t - off] : 0;
      __syncthreads();
      lds[t] += v; __syncthreads();
    }
    if (c0 + t < nchunk) bexcl[c0 + t] = running + lds[t] - x;
    running += lds[255];
    __syncthreads();
  }
  // minmax reduce
  float amin = 3.4e38f, amax = -3.4e38f, cmin = 3.4e38f, cmax = -3.4e38f;
  for (int i = t; i < nb; i += 256) {
    float4 p = partial[i];
    amin = fminf(amin, p.x); amax = fmaxf(amax, p.y);
    cmin = fminf(cmin, p.z); cmax = fmaxf(cmax, p.w);
  }
  #pragma unroll
  for (int off = 32; off; off >>= 1) {
    amin = fminf(amin, __shfl_down(amin, off));
    amax = fmaxf(amax, __shfl_down(amax, off));
    cmin = fminf(cmin, __shfl_down(cmin, off));
    cmax = fmaxf(cmax, __shfl_down(cmax, off));
  }
  __shared__ float4 lred[4];
  if ((t & 63) == 0) lred[t >> 6] = make_float4(amin, amax, cmin, cmax);
  __syncthreads();
  if (t == 0) {
    float4 r = lred[0];
    #pragma unroll
    for (int w = 1; w < 4; w++) {
      r.x = fminf(r.x, lred[w].x); r.y = fmaxf(r.y, lred[w].y);
      r.z = fminf(r.z, lred[w].z); r.w = fmaxf(r.w, lred[w].w);
    }
    mmf[0] = r.x; mmf[1] = r.y; mmf[2] = r.z; mmf[3] = r.w;
  }
}

// ---------- scan stage 3: per-chunk exclusive scan + base -> smat ----------
__global__ __launch_bounds__(256) void scan3_k(const int* __restrict__ v,
                                               const int* __restrict__ bexcl,
                                               int* __restrict__ smat, int M) {
  __shared__ int lds[256];
  int t = threadIdx.x, b = blockIdx.x;
  int running = bexcl[b];
  for (int tile = 0; tile < SCH; tile += 256) {
    int i = b * SCH + tile + t;
    int x = (i < M) ? v[i] : 0;
    lds[t] = x; __syncthreads();
    for (int off = 1; off < 256; off <<= 1) {
      int vv = (t >= off) ? lds[t - off] : 0;
      __syncthreads();
      lds[t] += vv; __syncthreads();
    }
    if (i < M) smat[i] = running + lds[t] - x;
    running += lds[255];
    __syncthreads();
  }
}

// ---------- scatter: LDS counting sort -> coalesced bucket-grouped payload ----------
// payload.x = dst | (fine << 20), payload.y = (edge_weight * log2e) bits
__global__ __launch_bounds__(256) void scatter_k(const int* __restrict__ src,
                                                 const int* __restrict__ dst,
                                                 const float* __restrict__ amount,
                                                 const float* __restrict__ count,
                                                 const float* __restrict__ mmf,
                                                 const int* __restrict__ smat,
                                                 int2* __restrict__ payload,
                                                 int E, int nblkA, int nbkt) {
  __shared__ int cntb[NBKTMX];
  __shared__ int baseb[NBKTMX];
  __shared__ int sbase[NBKTMX];
  __shared__ int tmp[256];
  __shared__ int2 lpay[CHUNKA];
  __shared__ int lgpos[CHUNKA];
  const int t = threadIdx.x, blk = blockIdx.x;
  for (int k = t; k < nbkt; k += 256) {
    cntb[k] = 0;
    sbase[k] = smat[(size_t)k * nblkA + blk];
  }
  __syncthreads();
  const float amin = mmf[0], amax = mmf[1], cmin = mmf[2], cmax = mmf[3];
  const float L2E = 1.4426950408889634f;
  const float ascale = 0.5f * L2E / (amax - amin + 1e-8f);
  const float cscale = 0.5f * L2E / (cmax - cmin + 1e-8f);
  int e0 = blk * CHUNKA + t * EPTA;
  const bool full = (e0 + EPTA <= E);
  int4 S[EPTA / 4]; int4 D[EPTA / 4]; float4 A[EPTA / 4]; float4 C[EPTA / 4];
  if (full) {
    #pragma unroll
    for (int q = 0; q < EPTA / 4; q++) {
      S[q] = *(const int4*)(src + e0 + 4 * q);
      D[q] = *(const int4*)(dst + e0 + 4 * q);
      A[q] = *(const float4*)(amount + e0 + 4 * q);
      C[q] = *(const float4*)(count + e0 + 4 * q);
      atomicAdd(&cntb[S[q].x >> BSHIFT], 1);
      atomicAdd(&cntb[S[q].y >> BSHIFT], 1);
      atomicAdd(&cntb[S[q].z >> BSHIFT], 1);
      atomicAdd(&cntb[S[q].w >> BSHIFT], 1);
    }
  } else {
    for (int e = e0; e < E; e++) atomicAdd(&cntb[src[e] >> BSHIFT], 1);
  }
  __syncthreads();
  // LDS exclusive scan of cntb[0..nbkt) -> baseb
  int running = 0;
  for (int c0 = 0; c0 < nbkt; c0 += 256) {
    int x = (c0 + t < nbkt) ? cntb[c0 + t] : 0;
    tmp[t] = x; __syncthreads();
    for (int off = 1; off < 256; off <<= 1) {
      int v = (t >= off) ? tmp[t - off] : 0;
      __syncthreads();
      tmp[t] += v; __syncthreads();
    }
    if (c0 + t < nbkt) baseb[c0 + t] = running + tmp[t] - x;
    running += tmp[255];
    __syncthreads();
  }
  for (int k = t; k < nbkt; k += 256) cntb[k] = baseb[k];
  __syncthreads();
  auto ins = [&](int s, int d, float a, float c) {
    int b = s >> BSHIFT;
    float ew = (a - amin) * ascale + (c - cmin) * cscale;
    int pos = atomicAdd(&cntb[b], 1);
    lpay[pos] = make_int2(d | ((s & BMASK) << 20), __float_as_int(ew));
    lgpos[pos] = sbase[b] + (pos - baseb[b]);
  };
  if (full) {
    #pragma unroll
    for (int q = 0; q < EPTA / 4; q++) {
      ins(S[q].x, D[q].x, A[q].x, C[q].x);
      ins(S[q].y, D[q].y, A[q].y, C[q].y);
      ins(S[q].z, D[q].z, A[q].z, C[q].z);
      ins(S[q].w, D[q].w, A[q].w, C[q].w);
    }
  } else {
    for (int e = e0; e < E; e++) ins(src[e], dst[e], amount[e], count[e]);
  }
  __syncthreads();
  const int ned = min(CHUNKA, E - blk * CHUNKA);
  for (int i = t; i < ned; i += 256) payload[lgpos[i]] = lpay[i];
}

// ---------- per-node projections: G1 fp32; P = half2(G2, h) ----------
__global__ __launch_bounds__(128) void pre_gemm(const float* __restrict__ h,
                                                const float* __restrict__ fc_w,
                                                const float* __restrict__ fc_b,
                                                float* __restrict__ G1,
                                                __half2* __restrict__ P, int N) {
  __shared__ float hs[NB * FDIM];
  const int t = threadIdx.x;
  const int o = t & 63, half = t >> 6;
  float w[FDIM];
  const float* wrow = fc_w + o * 128 + half * 64;
  #pragma unroll
  for (int f = 0; f < FDIM; f += 4) {
    float4 v = *(const float4*)(wrow + f);
    w[f] = v.x; w[f + 1] = v.y; w[f + 2] = v.z; w[f + 3] = v.w;
  }
  const float bias = (half == 0) ? fc_b[o] : 0.0f;
  const int n0 = blockIdx.x * NB;
  const int nrows = min(NB, N - n0);
  for (int i = t; i < nrows * FDIM; i += 128) hs[i] = h[(size_t)n0 * FDIM + i];
  __syncthreads();
  for (int n = 0; n < nrows; n++) {
    float acc = bias;
    #pragma unroll
    for (int f = 0; f < FDIM; f += 4) {
      float4 hv = *(const float4*)(&hs[n * FDIM + f]);
      acc += hv.x * w[f] + hv.y * w[f + 1] + hv.z * w[f + 2] + hv.w * w[f + 3];
    }
    if (half == 0) {
      G1[(size_t)(n0 + n) * FDIM + o] = acc;
    } else {
      P[(size_t)(n0 + n) * FDIM + o] =
          __halves2half2(__float2half(acc), __float2half(hs[n * FDIM + o]));
    }
  }
}

__device__ __forceinline__ float2 unpack_h2(unsigned u) {
  __half2 v = *(__half2*)&u;
  return make_float2(__low2float(v), __high2float(v));
}

// ---------- fused bucket pass: LDS accum per 64-node bucket, no CSR ----------
__global__ __launch_bounds__(256) void fused_k(const int2* __restrict__ payload,
                                               const int* __restrict__ smat,
                                               const float* __restrict__ G1,
                                               const unsigned* __restrict__ P,
                                               double* __restrict__ colsum,
                                               float* __restrict__ out,
                                               int E, int nblkA, int nbkt, int N) {
  __shared__ float g1s[64 * FDIM];    // bucket's G1 rows
  __shared__ float accum[64 * FDIM];  // fp32 accumulator
  __shared__ float part[256];
  const int t = threadIdx.x;
  const int lane = t & 63;
  const int wv = t >> 6;
  const int b = blockIdx.x;
  const int base = smat[(size_t)b * nblkA];
  const int end  = (b + 1 < nbkt) ? smat[(size_t)(b + 1) * nblkA] : E;
  const int n0 = b << BSHIFT;
  const int nmax = min(64, N - n0);
  // stage G1 rows + zero accum (float4)
  {
    const float4* Gsrc = (const float4*)(G1 + (size_t)n0 * FDIM);
    float4* g4 = (float4*)g1s;
    float4* a4 = (float4*)accum;
    const int tot4 = (nmax * FDIM) >> 2;
    for (int i = t; i < tot4; i += 256) g4[i] = Gsrc[i];
    const float4 z = make_float4(0.f, 0.f, 0.f, 0.f);
    for (int i = t; i < 64 * FDIM / 4; i += 256) a4[i] = z;
  }
  __syncthreads();
  float csum = 0.0f;
  for (int i0 = base + wv * 64; i0 < end; i0 += 256) {
    const int m = min(64, end - i0);
    int2 p = make_int2(0, 0);
    if (lane < m) p = payload[i0 + lane];
    if (m == 64) {
      #pragma unroll 1
      for (int j = 0; j < 64; j += 8) {
        #pragma unroll
        for (int k = 0; k < 8; k++) {
          int sx = __builtin_amdgcn_readlane(p.x, j + k);
          float ew = __int_as_float(__builtin_amdgcn_readlane(p.y, j + k));
          int f = sx >> 20;
          int d = sx & DMASK;
          float g1 = g1s[f * FDIM + lane];
          float2 v = unpack_h2(P[(size_t)d * FDIM + lane]);
          float sc = g1 + v.x;
          sc = fmaxf(sc, 0.01f * sc);                 // leaky_relu
          float x = exp2f(sc * ew);                   // log2e pre-folded into ew
          csum += x;
          atomicAdd(&accum[f * FDIM + lane], x * v.y);  // ds_add_f32
        }
      }
    } else {
      for (int j = 0; j < m; j += 8) {
        const int rem = m - j;
        #pragma unroll
        for (int k = 0; k < 8; k++) {
          int sx = __builtin_amdgcn_readlane(p.x, j + k);
          float ew = __int_as_float(__builtin_amdgcn_readlane(p.y, j + k));
          float wm = (k < rem) ? 1.0f : 0.0f;
          int f = sx >> 20;
          int d = sx & DMASK;
          float g1 = g1s[f * FDIM + lane];
          float2 v = unpack_h2(P[(size_t)d * FDIM + lane]);
          float sc = g1 + v.x;
          sc = fmaxf(sc, 0.01f * sc);
          float x = exp2f(sc * ew) * wm;
          csum += x;
          atomicAdd(&accum[f * FDIM + lane], x * v.y);
        }
      }
    }
  }
  __syncthreads();
  // write out (unnormalized) — coalesced float4
  {
    float4* osrc = (float4*)(out + (size_t)n0 * FDIM);
    const float4* a4 = (const float4*)accum;
    const int tot4 = (nmax * FDIM) >> 2;
    for (int i = t; i < tot4; i += 256) osrc[i] = a4[i];
  }
  part[t] = csum;
  __syncthreads();
  if (t < 64) {
    float tot = part[t] + part[t + 64] + part[t + 128] + part[t + 192];
    atomicAdd(&colsum[t * 16], (double)tot);   // 128B-padded per feature
  }
}

// ---------- epilogue: out *= 1/colsum[feature], float4 ----------
__global__ __launch_bounds__(256) void scale_k(float4* __restrict__ out4,
                                               const double* __restrict__ colsum,
                                               int total4) {
  __shared__ float rinv_s[64];
  if (threadIdx.x < 64) rinv_s[threadIdx.x] = (float)(1.0 / colsum[threadIdx.x * 16]);
  __syncthreads();
  const float4* r4 = (const float4*)rinv_s;
  int idx = blockIdx.x * blockDim.x + threadIdx.x;
  int stride = gridDim.x * blockDim.x;
  for (int i = idx; i < total4; i += stride) {
    float4 v = out4[i];
    float4 r = r4[i & 15];
    v.x *= r.x; v.y *= r.y; v.z *= r.z; v.w *= r.w;
    out4[i] = v;
  }
}

extern "C" void kernel_launch(void* const* d_in, const int* in_sizes, int n_in,
                              void* d_out, int out_size, void* d_ws, size_t ws_size,
                              hipStream_t stream) {
  const float* h      = (const float*)d_in[0];
  const int*   adj    = (const int*)d_in[1];
  const float* amount = (const float*)d_in[2];
  const float* count  = (const float*)d_in[3];
  const float* fc_w   = (const float*)d_in[4];
  const float* fc_b   = (const float*)d_in[5];
  float* out = (float*)d_out;

  const int E = in_sizes[2];
  const int N = in_sizes[0] / FDIM;
  const int* src = adj;
  const int* dst = adj + E;
  const int nbkt  = (N + BMASK) >> BSHIFT;           // 64-node buckets
  const int nblkA = (E + CHUNKA - 1) / CHUNKA;
  const int M = nbkt * nblkA;
  const int nchunk = (M + SCH - 1) / SCH;

  // ---- workspace layout (256B-aligned) ----
  char* ws = (char*)d_ws;
  size_t off = 0;
  auto alloc = [&](size_t bytes) { void* p = ws + off; off += (bytes + 255) & ~(size_t)255; return p; };
  float*    G1      = (float*)alloc((size_t)N * FDIM * sizeof(float));
  __half2*  P       = (__half2*)alloc((size_t)N * FDIM * sizeof(__half2));
  int2*     payload = (int2*)alloc((size_t)E * sizeof(int2));
  int*      mat     = (int*)alloc((size_t)M * sizeof(int));
  int*      smat    = (int*)alloc((size_t)M * sizeof(int));
  int*      bsum    = (int*)alloc((size_t)nchunk * sizeof(int));
  int*      bexcl   = (int*)alloc((size_t)nchunk * sizeof(int));
  float4*   mmpart  = (float4*)alloc((size_t)nblkA * sizeof(float4));
  double*   colsum  = (double*)alloc(1024 * sizeof(double));  // padded: [f*16]
  float*    mmf     = (float*)alloc(4 * sizeof(float));

  count_mm_k<<<nblkA, 256, 0, stream>>>(src, amount, count, mat, mmpart, colsum, E, nblkA, nbkt);
  scan1_k<<<nchunk, 256, 0, stream>>>(mat, bsum, M);
  scan2_k<<<1, 256, 0, stream>>>(bsum, bexcl, nchunk, mmpart, mmf, nblkA);
  scan3_k<<<nchunk, 256, 0, stream>>>(mat, bexcl, smat, M);
  scatter_k<<<nblkA, 256, 0, stream>>>(src, dst, amount, count, mmf, smat, payload, E, nblkA, nbkt);
  pre_gemm<<<(N + NB - 1) / NB, 128, 0, stream>>>(h, fc_w, fc_b, G1, P, N);
  fused_k<<<nbkt, 256, 0, stream>>>(payload, smat, G1, (const unsigned*)P, colsum, out, E, nblkA, nbkt, N);
  scale_k<<<1024, 256, 0, stream>>>((float4*)out, colsum, N * FDIM / 4);
}

// Round 10
// 306.785 us; speedup vs baseline: 3.2037x; 3.2037x over previous
//
#include <hip/hip_runtime.h>
#include <hip/hip_fp16.h>
#include <math.h>

#define FDIM   64
#define NB     16      // nodes per block in pre_gemm
#define BSHIFT 7       // coarse bucket = 128 nodes
#define BMASK  127
#define EPTA   16      // edges per thread in binA
#define CHUNKA (EPTA * 256)   // 4096
#define SCH    1024    // scan chunk
#define DMASK  0xFFFFF // dst fits in 20 bits (N = 100000 < 2^20)

// ---------- binA count + minmax partial + zero colsum (one edge sweep) ----------
__global__ __launch_bounds__(256) void count_mm_k(const int* __restrict__ src,
                                                  const float* __restrict__ amount,
                                                  const float* __restrict__ count,
                                                  int* __restrict__ mat,
                                                  float4* __restrict__ partial,
                                                  double* __restrict__ colsum,
                                                  int E, int nblkA, int nbkt) {
  __shared__ int lhist[1024];
  __shared__ float4 lred[4];
  for (int k = threadIdx.x; k < nbkt; k += 256) lhist[k] = 0;
  if (blockIdx.x == 0)
    for (int i = threadIdx.x; i < 1024; i += 256) colsum[i] = 0.0;
  __syncthreads();
  float amin = 3.4e38f, amax = -3.4e38f, cmin = 3.4e38f, cmax = -3.4e38f;
  int e0 = blockIdx.x * CHUNKA + threadIdx.x * EPTA;
  if (e0 + EPTA <= E) {
    #pragma unroll
    for (int q = 0; q < EPTA; q += 4) {
      int4   s4 = *(const int4*)(src + e0 + q);
      float4 a4 = *(const float4*)(amount + e0 + q);
      float4 c4 = *(const float4*)(count + e0 + q);
      atomicAdd(&lhist[s4.x >> BSHIFT], 1);
      atomicAdd(&lhist[s4.y >> BSHIFT], 1);
      atomicAdd(&lhist[s4.z >> BSHIFT], 1);
      atomicAdd(&lhist[s4.w >> BSHIFT], 1);
      amin = fminf(amin, fminf(fminf(a4.x, a4.y), fminf(a4.z, a4.w)));
      amax = fmaxf(amax, fmaxf(fmaxf(a4.x, a4.y), fmaxf(a4.z, a4.w)));
      cmin = fminf(cmin, fminf(fminf(c4.x, c4.y), fminf(c4.z, c4.w)));
      cmax = fmaxf(cmax, fmaxf(fmaxf(c4.x, c4.y), fmaxf(c4.z, c4.w)));
    }
  } else {
    for (int e = e0; e < E; e++) {
      atomicAdd(&lhist[src[e] >> BSHIFT], 1);
      float a = amount[e], c = count[e];
      amin = fminf(amin, a); amax = fmaxf(amax, a);
      cmin = fminf(cmin, c); cmax = fmaxf(cmax, c);
    }
  }
  #pragma unroll
  for (int off = 32; off; off >>= 1) {
    amin = fminf(amin, __shfl_down(amin, off));
    amax = fmaxf(amax, __shfl_down(amax, off));
    cmin = fminf(cmin, __shfl_down(cmin, off));
    cmax = fmaxf(cmax, __shfl_down(cmax, off));
  }
  if ((threadIdx.x & 63) == 0) lred[threadIdx.x >> 6] = make_float4(amin, amax, cmin, cmax);
  __syncthreads();
  for (int k = threadIdx.x; k < nbkt; k += 256)
    mat[(size_t)k * nblkA + blockIdx.x] = lhist[k];
  if (threadIdx.x == 0) {
    float4 r = lred[0];
    #pragma unroll
    for (int w = 1; w < 4; w++) {
      r.x = fminf(r.x, lred[w].x); r.y = fmaxf(r.y, lred[w].y);
      r.z = fminf(r.z, lred[w].z); r.w = fmaxf(r.w, lred[w].w);
    }
    partial[blockIdx.x] = r;
  }
}

// ---------- scan stage 1: per-chunk sums ----------
__global__ __launch_bounds__(256) void scan1_k(const int* __restrict__ v,
                                               int* __restrict__ bsum, int M) {
  __shared__ int lds[256];
  int t = threadIdx.x, b = blockIdx.x;
  int s = 0;
  for (int i = b * SCH + t; i < min((b + 1) * SCH, M); i += 256) s += v[i];
  lds[t] = s; __syncthreads();
  for (int off = 128; off; off >>= 1) {
    if (t < off) lds[t] += lds[t + off];
    __syncthreads();
  }
  if (t == 0) bsum[b] = lds[0];
}

// ---------- scan stage 2 + minmax final reduce (1 block) ----------
__global__ __launch_bounds__(256) void scan2_k(const int* __restrict__ bsum,
                                               int* __restrict__ bexcl, int nchunk,
                                               const float4* __restrict__ partial,
                                               float* __restrict__ mmf, int nb) {
  __shared__ int lds[256];
  int t = threadIdx.x;
  int running = 0;
  for (int c0 = 0; c0 < nchunk; c0 += 256) {
    int x = (c0 + t < nchunk) ? bsum[c0 + t] : 0;
    lds[t] = x; __syncthreads();
    for (int off = 1; off < 256; off <<= 1) {
      int v = (t >= off) ? lds[t - off] : 0;
      __syncthreads();
      lds[t] += v; __syncthreads();
    }
    if (c0 + t < nchunk) bexcl[c0 + t] = running + lds[t] - x;
    running += lds[255];
    __syncthreads();
  }
  float amin = 3.4e38f, amax = -3.4e38f, cmin = 3.4e38f, cmax = -3.4e38f;
  for (int i = t; i < nb; i += 256) {
    float4 p = partial[i];
    amin = fminf(amin, p.x); amax = fmaxf(amax, p.y);
    cmin = fminf(cmin, p.z); cmax = fmaxf(cmax, p.w);
  }
  #pragma unroll
  for (int off = 32; off; off >>= 1) {
    amin = fminf(amin, __shfl_down(amin, off));
    amax = fmaxf(amax, __shfl_down(amax, off));
    cmin = fminf(cmin, __shfl_down(cmin, off));
    cmax = fmaxf(cmax, __shfl_down(cmax, off));
  }
  __shared__ float4 lred[4];
  if ((t & 63) == 0) lred[t >> 6] = make_float4(amin, amax, cmin, cmax);
  __syncthreads();
  if (t == 0) {
    float4 r = lred[0];
    #pragma unroll
    for (int w = 1; w < 4; w++) {
      r.x = fminf(r.x, lred[w].x); r.y = fmaxf(r.y, lred[w].y);
      r.z = fminf(r.z, lred[w].z); r.w = fmaxf(r.w, lred[w].w);
    }
    mmf[0] = r.x; mmf[1] = r.y; mmf[2] = r.z; mmf[3] = r.w;
  }
}

// ---------- scan stage 3: per-chunk exclusive scan + base -> smat ----------
__global__ __launch_bounds__(256) void scan3_k(const int* __restrict__ v,
                                               const int* __restrict__ bexcl,
                                               int* __restrict__ smat, int M) {
  __shared__ int lds[256];
  int t = threadIdx.x, b = blockIdx.x;
  int running = bexcl[b];
  for (int tile = 0; tile < SCH; tile += 256) {
    int i = b * SCH + tile + t;
    int x = (i < M) ? v[i] : 0;
    lds[t] = x; __syncthreads();
    for (int off = 1; off < 256; off <<= 1) {
      int vv = (t >= off) ? lds[t - off] : 0;
      __syncthreads();
      lds[t] += vv; __syncthreads();
    }
    if (i < M) smat[i] = running + lds[t] - x;
    running += lds[255];
    __syncthreads();
  }
}

// ---------- scatter: LDS counting sort -> coalesced bucket-grouped payload ----------
// payload.x = dst | (fine << 20), payload.y = (edge_weight * log2e) bits
__global__ __launch_bounds__(256) void scatter_k(const int* __restrict__ src,
                                                 const int* __restrict__ dst,
                                                 const float* __restrict__ amount,
                                                 const float* __restrict__ count,
                                                 const float* __restrict__ mmf,
                                                 const int* __restrict__ smat,
                                                 int2* __restrict__ payload,
                                                 int E, int nblkA, int nbkt) {
  __shared__ int cntb[1024];
  __shared__ int baseb[1024];
  __shared__ int sbase[1024];
  __shared__ int tmp[256];
  __shared__ int2 lpay[CHUNKA];
  __shared__ int lgpos[CHUNKA];
  const int t = threadIdx.x, blk = blockIdx.x;
  for (int k = t; k < nbkt; k += 256) {
    cntb[k] = 0;
    sbase[k] = smat[(size_t)k * nblkA + blk];
  }
  __syncthreads();
  const float amin = mmf[0], amax = mmf[1], cmin = mmf[2], cmax = mmf[3];
  const float L2E = 1.4426950408889634f;
  const float ascale = 0.5f * L2E / (amax - amin + 1e-8f);
  const float cscale = 0.5f * L2E / (cmax - cmin + 1e-8f);
  int e0 = blk * CHUNKA + t * EPTA;
  const bool full = (e0 + EPTA <= E);
  int4 S[4]; int4 D[4]; float4 A[4]; float4 C[4];
  if (full) {
    #pragma unroll
    for (int q = 0; q < 4; q++) {
      S[q] = *(const int4*)(src + e0 + 4 * q);
      D[q] = *(const int4*)(dst + e0 + 4 * q);
      A[q] = *(const float4*)(amount + e0 + 4 * q);
      C[q] = *(const float4*)(count + e0 + 4 * q);
      atomicAdd(&cntb[S[q].x >> BSHIFT], 1);
      atomicAdd(&cntb[S[q].y >> BSHIFT], 1);
      atomicAdd(&cntb[S[q].z >> BSHIFT], 1);
      atomicAdd(&cntb[S[q].w >> BSHIFT], 1);
    }
  } else {
    for (int e = e0; e < E; e++) atomicAdd(&cntb[src[e] >> BSHIFT], 1);
  }
  __syncthreads();
  int running = 0;
  for (int c0 = 0; c0 < nbkt; c0 += 256) {
    int x = (c0 + t < nbkt) ? cntb[c0 + t] : 0;
    tmp[t] = x; __syncthreads();
    for (int off = 1; off < 256; off <<= 1) {
      int v = (t >= off) ? tmp[t - off] : 0;
      __syncthreads();
      tmp[t] += v; __syncthreads();
    }
    if (c0 + t < nbkt) baseb[c0 + t] = running + tmp[t] - x;
    running += tmp[255];
    __syncthreads();
  }
  for (int k = t; k < nbkt; k += 256) cntb[k] = baseb[k];
  __syncthreads();
  auto ins = [&](int s, int d, float a, float c) {
    int b = s >> BSHIFT;
    float ew = (a - amin) * ascale + (c - cmin) * cscale;
    int pos = atomicAdd(&cntb[b], 1);
    lpay[pos] = make_int2(d | ((s & BMASK) << 20), __float_as_int(ew));
    lgpos[pos] = sbase[b] + (pos - baseb[b]);
  };
  if (full) {
    #pragma unroll
    for (int q = 0; q < 4; q++) {
      ins(S[q].x, D[q].x, A[q].x, C[q].x);
      ins(S[q].y, D[q].y, A[q].y, C[q].y);
      ins(S[q].z, D[q].z, A[q].z, C[q].z);
      ins(S[q].w, D[q].w, A[q].w, C[q].w);
    }
  } else {
    for (int e = e0; e < E; e++) ins(src[e], dst[e], amount[e], count[e]);
  }
  __syncthreads();
  const int ned = min(CHUNKA, E - blk * CHUNKA);
  for (int i = t; i < ned; i += 256) payload[lgpos[i]] = lpay[i];
}

// ---------- binB: per-bucket fine counting sort -> edge_s, hist, offsets ----------
__global__ __launch_bounds__(256) void binB_k(const int2* __restrict__ payload,
                                              const int* __restrict__ smat,
                                              int* __restrict__ hist,
                                              int* __restrict__ offsets,
                                              int2* __restrict__ edge_s,
                                              int E, int nblkA, int nbkt, int N) {
  __shared__ int fcnt[128];
  __shared__ int fs[128];
  __shared__ int fcur[128];
  const int b = blockIdx.x;
  const int t = threadIdx.x;
  const int base = smat[(size_t)b * nblkA];
  const int end  = (b + 1 < nbkt) ? smat[(size_t)(b + 1) * nblkA] : E;
  if (t < 128) fcnt[t] = 0;
  __syncthreads();
  for (int i = base + t; i < end; i += 256)
    atomicAdd(&fcnt[payload[i].x >> 20], 1);
  __syncthreads();
  if (t < 128) fs[t] = fcnt[t];
  __syncthreads();
  for (int off = 1; off < 128; off <<= 1) {
    int v = 0;
    if (t < 128 && t >= off) v = fs[t - off];
    __syncthreads();
    if (t < 128) fs[t] += v;
    __syncthreads();
  }
  if (t < 128) {
    int excl = fs[t] - fcnt[t];
    fcur[t] = base + excl;
    int node = (b << BSHIFT) + t;
    if (node < N) { hist[node] = fcnt[t]; offsets[node] = base + excl; }
  }
  __syncthreads();
  for (int i = base + t; i < end; i += 256) {
    int2 v = payload[i];
    int pos = atomicAdd(&fcur[v.x >> 20], 1);
    edge_s[pos] = make_int2(v.x & DMASK, v.y);
  }
}

// ---------- per-node projections: G1 fp32; P = half2(G2, h) ----------
__global__ __launch_bounds__(128) void pre_gemm(const float* __restrict__ h,
                                                const float* __restrict__ fc_w,
                                                const float* __restrict__ fc_b,
                                                float* __restrict__ G1,
                                                __half2* __restrict__ P, int N) {
  __shared__ float hs[NB * FDIM];
  const int t = threadIdx.x;
  const int o = t & 63, half = t >> 6;
  float w[FDIM];
  const float* wrow = fc_w + o * 128 + half * 64;
  #pragma unroll
  for (int f = 0; f < FDIM; f += 4) {
    float4 v = *(const float4*)(wrow + f);
    w[f] = v.x; w[f + 1] = v.y; w[f + 2] = v.z; w[f + 3] = v.w;
  }
  const float bias = (half == 0) ? fc_b[o] : 0.0f;
  const int n0 = blockIdx.x * NB;
  const int nrows = min(NB, N - n0);
  for (int i = t; i < nrows * FDIM; i += 128) hs[i] = h[(size_t)n0 * FDIM + i];
  __syncthreads();
  for (int n = 0; n < nrows; n++) {
    float acc = bias;
    #pragma unroll
    for (int f = 0; f < FDIM; f += 4) {
      float4 hv = *(const float4*)(&hs[n * FDIM + f]);
      acc += hv.x * w[f] + hv.y * w[f + 1] + hv.z * w[f + 2] + hv.w * w[f + 3];
    }
    if (half == 0) {
      G1[(size_t)(n0 + n) * FDIM + o] = acc;
    } else {
      P[(size_t)(n0 + n) * FDIM + o] =
          __halves2half2(__float2half(acc), __float2half(hs[n * FDIM + o]));
    }
  }
}

__device__ __forceinline__ float2 unpack_h2(unsigned u) {
  __half2 v = *(__half2*)&u;
  return make_float2(__low2float(v), __high2float(v));
}

// ---------- fused edge pass: per-node CSR, register acc, 16-wide gather MLP ----------
__global__ __launch_bounds__(256) void fused_k(const int* __restrict__ offsets,
                                               const int* __restrict__ hist,
                                               const int2* __restrict__ edge_s,
                                               const float* __restrict__ G1,
                                               const unsigned* __restrict__ P,
                                               double* __restrict__ colsum,
                                               float* __restrict__ out, int N) {
  const int lane = threadIdx.x & 63;
  const int wid = blockIdx.x * 4 + (threadIdx.x >> 6);
  const int nw = gridDim.x * 4;
  float csum = 0.0f;
  for (int n = wid; n < N; n += nw) {
    float g1 = G1[(size_t)n * FDIM + lane];
    float acc = 0.0f;
    int start = offsets[n], cnt = hist[n];
    for (int j0 = 0; j0 < cnt; j0 += 64) {
      int m = min(64, cnt - j0);
      int2 p = make_int2(0, 0);   // lane>=m: d=0, ew=0 -> exp2(0)=1, masked by wm
      if (lane < m) p = edge_s[start + j0 + lane];
      int j = 0;
      for (; j + 16 <= m; j += 16) {   // full 16-wide: 16 gathers in flight
        int dd[16]; float ee[16]; unsigned uu[16];
        #pragma unroll
        for (int k = 0; k < 16; k++) {
          dd[k] = __builtin_amdgcn_readlane(p.x, j + k);
          ee[k] = __int_as_float(__builtin_amdgcn_readlane(p.y, j + k));
        }
        #pragma unroll
        for (int k = 0; k < 16; k++) uu[k] = P[(size_t)dd[k] * FDIM + lane];
        #pragma unroll
        for (int k = 0; k < 16; k++) {
          float2 v = unpack_h2(uu[k]);
          float sc = g1 + v.x;
          sc = fmaxf(sc, 0.01f * sc);          // leaky_relu
          float x = exp2f(sc * ee[k]);         // log2e pre-folded into ew
          csum += x;
          acc += x * v.y;
        }
      }
      for (; j < m; j += 8) {          // masked 8-wide tail
        int rem = m - j;
        int dd[8]; float ee[8], wm[8]; unsigned uu[8];
        #pragma unroll
        for (int k = 0; k < 8; k++) {
          dd[k] = __builtin_amdgcn_readlane(p.x, j + k);
          ee[k] = __int_as_float(__builtin_amdgcn_readlane(p.y, j + k));
          wm[k] = (k < rem) ? 1.0f : 0.0f;
        }
        #pragma unroll
        for (int k = 0; k < 8; k++) uu[k] = P[(size_t)dd[k] * FDIM + lane];
        #pragma unroll
        for (int k = 0; k < 8; k++) {
          float2 v = unpack_h2(uu[k]);
          float sc = g1 + v.x;
          sc = fmaxf(sc, 0.01f * sc);
          float x = exp2f(sc * ee[k]) * wm[k];
          csum += x;
          acc += x * v.y;
        }
      }
    }
    out[(size_t)n * FDIM + lane] = acc;  // unnormalized; scaled by scale_k
  }
  __shared__ float part[256];
  part[threadIdx.x] = csum;
  __syncthreads();
  if (threadIdx.x < 64) {
    float tot = part[threadIdx.x] + part[threadIdx.x + 64] +
                part[threadIdx.x + 128] + part[threadIdx.x + 192];
    atomicAdd(&colsum[threadIdx.x * 16], (double)tot);   // 128B line per feature
  }
}

// ---------- epilogue: out *= 1/colsum[feature], float4 ----------
__global__ __launch_bounds__(256) void scale_k(float4* __restrict__ out4,
                                               const double* __restrict__ colsum,
                                               int total4) {
  __shared__ float rinv_s[64];
  if (threadIdx.x < 64) rinv_s[threadIdx.x] = (float)(1.0 / colsum[threadIdx.x * 16]);
  __syncthreads();
  const float4* r4 = (const float4*)rinv_s;
  int idx = blockIdx.x * blockDim.x + threadIdx.x;
  int stride = gridDim.x * blockDim.x;
  for (int i = idx; i < total4; i += stride) {
    float4 v = out4[i];
    float4 r = r4[i & 15];
    v.x *= r.x; v.y *= r.y; v.z *= r.z; v.w *= r.w;
    out4[i] = v;
  }
}

extern "C" void kernel_launch(void* const* d_in, const int* in_sizes, int n_in,
                              void* d_out, int out_size, void* d_ws, size_t ws_size,
                              hipStream_t stream) {
  const float* h      = (const float*)d_in[0];
  const int*   adj    = (const int*)d_in[1];
  const float* amount = (const float*)d_in[2];
  const float* count  = (const float*)d_in[3];
  const float* fc_w   = (const float*)d_in[4];
  const float* fc_b   = (const float*)d_in[5];
  float* out = (float*)d_out;

  const int E = in_sizes[2];
  const int N = in_sizes[0] / FDIM;
  const int* src = adj;
  const int* dst = adj + E;
  const int nbkt  = (N + BMASK) >> BSHIFT;           // 128-node buckets (<=1024)
  const int nblkA = (E + CHUNKA - 1) / CHUNKA;
  const int M = nbkt * nblkA;
  const int nchunk = (M + SCH - 1) / SCH;

  // ---- workspace layout (256B-aligned) ----
  char* ws = (char*)d_ws;
  size_t off = 0;
  auto alloc = [&](size_t bytes) { void* p = ws + off; off += (bytes + 255) & ~(size_t)255; return p; };
  float*    G1      = (float*)alloc((size_t)N * FDIM * sizeof(float));
  __half2*  P       = (__half2*)alloc((size_t)N * FDIM * sizeof(__half2));
  int2*     edge_s  = (int2*)alloc((size_t)E * sizeof(int2));
  int2*     payload = (int2*)alloc((size_t)E * sizeof(int2));
  int*      hist    = (int*)alloc((size_t)N * sizeof(int));
  int*      offsets = (int*)alloc((size_t)N * sizeof(int));
  int*      mat     = (int*)alloc((size_t)M * sizeof(int));
  int*      smat    = (int*)alloc((size_t)M * sizeof(int));
  int*      bsum    = (int*)alloc((size_t)nchunk * sizeof(int));
  int*      bexcl   = (int*)alloc((size_t)nchunk * sizeof(int));
  float4*   mmpart  = (float4*)alloc((size_t)nblkA * sizeof(float4));
  double*   colsum  = (double*)alloc(1024 * sizeof(double));   // padded: [f*16]
  float*    mmf     = (float*)alloc(4 * sizeof(float));

  count_mm_k<<<nblkA, 256, 0, stream>>>(src, amount, count, mat, mmpart, colsum, E, nblkA, nbkt);
  scan1_k<<<nchunk, 256, 0, stream>>>(mat, bsum, M);
  scan2_k<<<1, 256, 0, stream>>>(bsum, bexcl, nchunk, mmpart, mmf, nblkA);
  scan3_k<<<nchunk, 256, 0, stream>>>(mat, bexcl, smat, M);
  scatter_k<<<nblkA, 256, 0, stream>>>(src, dst, amount, count, mmf, smat, payload, E, nblkA, nbkt);
  binB_k<<<nbkt, 256, 0, stream>>>(payload, smat, hist, offsets, edge_s, E, nblkA, nbkt, N);
  pre_gemm<<<(N + NB - 1) / NB, 128, 0, stream>>>(h, fc_w, fc_b, G1, P, N);
  fused_k<<<4096, 256, 0, stream>>>(offsets, hist, edge_s, G1, (const unsigned*)P, colsum, out, N);
  scale_k<<<1024, 256, 0, stream>>>((float4*)out, colsum, N * FDIM / 4);
}

// Round 11
// 302.728 us; speedup vs baseline: 3.2466x; 1.0134x over previous
//
#include <hip/hip_runtime.h>
#include <hip/hip_fp16.h>
#include <math.h>

#define FDIM   64
#define NB     16      // nodes per block in pre_gemm
#define BSHIFT 7       // coarse bucket = 128 nodes
#define BMASK  127
#define EPTA   16      // edges per thread in binA
#define CHUNKA (EPTA * 256)   // 4096
#define SCH    1024    // scan chunk
#define DMASK  0xFFFFF // dst fits in 20 bits (N = 100000 < 2^20)

// ---------- binA count + minmax partial + zero colsum (one edge sweep) ----------
__global__ __launch_bounds__(256) void count_mm_k(const int* __restrict__ src,
                                                  const float* __restrict__ amount,
                                                  const float* __restrict__ count,
                                                  int* __restrict__ mat,
                                                  float4* __restrict__ partial,
                                                  double* __restrict__ colsum,
                                                  int E, int nblkA, int nbkt) {
  __shared__ int lhist[1024];
  __shared__ float4 lred[4];
  for (int k = threadIdx.x; k < nbkt; k += 256) lhist[k] = 0;
  if (blockIdx.x == 0)
    for (int i = threadIdx.x; i < 1024; i += 256) colsum[i] = 0.0;
  __syncthreads();
  float amin = 3.4e38f, amax = -3.4e38f, cmin = 3.4e38f, cmax = -3.4e38f;
  int e0 = blockIdx.x * CHUNKA + threadIdx.x * EPTA;
  if (e0 + EPTA <= E) {
    #pragma unroll
    for (int q = 0; q < EPTA; q += 4) {
      int4   s4 = *(const int4*)(src + e0 + q);
      float4 a4 = *(const float4*)(amount + e0 + q);
      float4 c4 = *(const float4*)(count + e0 + q);
      atomicAdd(&lhist[s4.x >> BSHIFT], 1);
      atomicAdd(&lhist[s4.y >> BSHIFT], 1);
      atomicAdd(&lhist[s4.z >> BSHIFT], 1);
      atomicAdd(&lhist[s4.w >> BSHIFT], 1);
      amin = fminf(amin, fminf(fminf(a4.x, a4.y), fminf(a4.z, a4.w)));
      amax = fmaxf(amax, fmaxf(fmaxf(a4.x, a4.y), fmaxf(a4.z, a4.w)));
      cmin = fminf(cmin, fminf(fminf(c4.x, c4.y), fminf(c4.z, c4.w)));
      cmax = fmaxf(cmax, fmaxf(fmaxf(c4.x, c4.y), fmaxf(c4.z, c4.w)));
    }
  } else {
    for (int e = e0; e < E; e++) {
      atomicAdd(&lhist[src[e] >> BSHIFT], 1);
      float a = amount[e], c = count[e];
      amin = fminf(amin, a); amax = fmaxf(amax, a);
      cmin = fminf(cmin, c); cmax = fmaxf(cmax, c);
    }
  }
  #pragma unroll
  for (int off = 32; off; off >>= 1) {
    amin = fminf(amin, __shfl_down(amin, off));
    amax = fmaxf(amax, __shfl_down(amax, off));
    cmin = fminf(cmin, __shfl_down(cmin, off));
    cmax = fmaxf(cmax, __shfl_down(cmax, off));
  }
  if ((threadIdx.x & 63) == 0) lred[threadIdx.x >> 6] = make_float4(amin, amax, cmin, cmax);
  __syncthreads();
  for (int k = threadIdx.x; k < nbkt; k += 256)
    mat[(size_t)k * nblkA + blockIdx.x] = lhist[k];
  if (threadIdx.x == 0) {
    float4 r = lred[0];
    #pragma unroll
    for (int w = 1; w < 4; w++) {
      r.x = fminf(r.x, lred[w].x); r.y = fmaxf(r.y, lred[w].y);
      r.z = fminf(r.z, lred[w].z); r.w = fmaxf(r.w, lred[w].w);
    }
    partial[blockIdx.x] = r;
  }
}

// ---------- scan stage 1: per-chunk sums ----------
__global__ __launch_bounds__(256) void scan1_k(const int* __restrict__ v,
                                               int* __restrict__ bsum, int M) {
  __shared__ int lds[256];
  int t = threadIdx.x, b = blockIdx.x;
  int s = 0;
  for (int i = b * SCH + t; i < min((b + 1) * SCH, M); i += 256) s += v[i];
  lds[t] = s; __syncthreads();
  for (int off = 128; off; off >>= 1) {
    if (t < off) lds[t] += lds[t + off];
    __syncthreads();
  }
  if (t == 0) bsum[b] = lds[0];
}

// ---------- scan stage 2 + minmax final reduce (1 block) ----------
__global__ __launch_bounds__(256) void scan2_k(const int* __restrict__ bsum,
                                               int* __restrict__ bexcl, int nchunk,
                                               const float4* __restrict__ partial,
                                               float* __restrict__ mmf, int nb) {
  __shared__ int lds[256];
  int t = threadIdx.x;
  int running = 0;
  for (int c0 = 0; c0 < nchunk; c0 += 256) {
    int x = (c0 + t < nchunk) ? bsum[c0 + t] : 0;
    lds[t] = x; __syncthreads();
    for (int off = 1; off < 256; off <<= 1) {
      int v = (t >= off) ? lds[t - off] : 0;
      __syncthreads();
      lds[t] += v; __syncthreads();
    }
    if (c0 + t < nchunk) bexcl[c0 + t] = running + lds[t] - x;
    running += lds[255];
    __syncthreads();
  }
  float amin = 3.4e38f, amax = -3.4e38f, cmin = 3.4e38f, cmax = -3.4e38f;
  for (int i = t; i < nb; i += 256) {
    float4 p = partial[i];
    amin = fminf(amin, p.x); amax = fmaxf(amax, p.y);
    cmin = fminf(cmin, p.z); cmax = fmaxf(cmax, p.w);
  }
  #pragma unroll
  for (int off = 32; off; off >>= 1) {
    amin = fminf(amin, __shfl_down(amin, off));
    amax = fmaxf(amax, __shfl_down(amax, off));
    cmin = fminf(cmin, __shfl_down(cmin, off));
    cmax = fmaxf(cmax, __shfl_down(cmax, off));
  }
  __shared__ float4 lred[4];
  if ((t & 63) == 0) lred[t >> 6] = make_float4(amin, amax, cmin, cmax);
  __syncthreads();
  if (t == 0) {
    float4 r = lred[0];
    #pragma unroll
    for (int w = 1; w < 4; w++) {
      r.x = fminf(r.x, lred[w].x); r.y = fmaxf(r.y, lred[w].y);
      r.z = fminf(r.z, lred[w].z); r.w = fmaxf(r.w, lred[w].w);
    }
    mmf[0] = r.x; mmf[1] = r.y; mmf[2] = r.z; mmf[3] = r.w;
  }
}

// ---------- scan stage 3: per-chunk exclusive scan + base -> smat ----------
__global__ __launch_bounds__(256) void scan3_k(const int* __restrict__ v,
                                               const int* __restrict__ bexcl,
                                               int* __restrict__ smat, int M) {
  __shared__ int lds[256];
  int t = threadIdx.x, b = blockIdx.x;
  int running = bexcl[b];
  for (int tile = 0; tile < SCH; tile += 256) {
    int i = b * SCH + tile + t;
    int x = (i < M) ? v[i] : 0;
    lds[t] = x; __syncthreads();
    for (int off = 1; off < 256; off <<= 1) {
      int vv = (t >= off) ? lds[t - off] : 0;
      __syncthreads();
      lds[t] += vv; __syncthreads();
    }
    if (i < M) smat[i] = running + lds[t] - x;
    running += lds[255];
    __syncthreads();
  }
}

// ---------- scatter: LDS counting sort -> coalesced bucket-grouped payload ----------
// payload.x = dst | (fine << 20), payload.y = (edge_weight * log2e) bits
__global__ __launch_bounds__(256) void scatter_k(const int* __restrict__ src,
                                                 const int* __restrict__ dst,
                                                 const float* __restrict__ amount,
                                                 const float* __restrict__ count,
                                                 const float* __restrict__ mmf,
                                                 const int* __restrict__ smat,
                                                 int2* __restrict__ payload,
                                                 int E, int nblkA, int nbkt) {
  __shared__ int cntb[1024];
  __shared__ int baseb[1024];
  __shared__ int sbase[1024];
  __shared__ int wsum[4];
  __shared__ int2 lpay[CHUNKA];
  __shared__ int lgpos[CHUNKA];
  const int t = threadIdx.x, blk = blockIdx.x;
  for (int k = t; k < nbkt; k += 256) {
    cntb[k] = 0;
    sbase[k] = smat[(size_t)k * nblkA + blk];
  }
  __syncthreads();
  const float amin = mmf[0], amax = mmf[1], cmin = mmf[2], cmax = mmf[3];
  const float L2E = 1.4426950408889634f;
  const float ascale = 0.5f * L2E / (amax - amin + 1e-8f);
  const float cscale = 0.5f * L2E / (cmax - cmin + 1e-8f);
  int e0 = blk * CHUNKA + t * EPTA;
  const bool full = (e0 + EPTA <= E);
  int4 S[4]; int4 D[4]; float4 A[4]; float4 C[4];
  if (full) {
    #pragma unroll
    for (int q = 0; q < 4; q++) {
      S[q] = *(const int4*)(src + e0 + 4 * q);
      D[q] = *(const int4*)(dst + e0 + 4 * q);
      A[q] = *(const float4*)(amount + e0 + 4 * q);
      C[q] = *(const float4*)(count + e0 + 4 * q);
      atomicAdd(&cntb[S[q].x >> BSHIFT], 1);
      atomicAdd(&cntb[S[q].y >> BSHIFT], 1);
      atomicAdd(&cntb[S[q].z >> BSHIFT], 1);
      atomicAdd(&cntb[S[q].w >> BSHIFT], 1);
    }
  } else {
    for (int e = e0; e < E; e++) atomicAdd(&cntb[src[e] >> BSHIFT], 1);
  }
  __syncthreads();
  // exclusive scan of cntb[0..nbkt) -> baseb : wave-shuffle scan, 2 barriers
  {
    const int wv = t >> 6, ln = t & 63;
    int carry = 0;
    #pragma unroll
    for (int c = 0; c < 4; c++) {
      int idx = (wv << 8) + (c << 6) + ln;
      int x = (idx < nbkt) ? cntb[idx] : 0;
      int v = x;
      #pragma unroll
      for (int off = 1; off < 64; off <<= 1) {
        int u = __shfl_up(v, off);
        if (ln >= off) v += u;
      }
      if (idx < nbkt) baseb[idx] = carry + v - x;
      carry += __shfl(v, 63);
    }
    if (ln == 0) wsum[wv] = carry;
  }
  __syncthreads();
  {
    const int wv = t >> 6, ln = t & 63;
    int wpre = 0;
    #pragma unroll
    for (int i = 0; i < 4; i++) wpre += (i < wv) ? wsum[i] : 0;
    if (wpre) {
      #pragma unroll
      for (int c = 0; c < 4; c++) {
        int idx = (wv << 8) + (c << 6) + ln;
        if (idx < nbkt) baseb[idx] += wpre;
      }
    }
  }
  __syncthreads();
  for (int k = t; k < nbkt; k += 256) cntb[k] = baseb[k];
  __syncthreads();
  auto ins = [&](int s, int d, float a, float c) {
    int b = s >> BSHIFT;
    float ew = (a - amin) * ascale + (c - cmin) * cscale;
    int pos = atomicAdd(&cntb[b], 1);
    lpay[pos] = make_int2(d | ((s & BMASK) << 20), __float_as_int(ew));
    lgpos[pos] = sbase[b] + (pos - baseb[b]);
  };
  if (full) {
    #pragma unroll
    for (int q = 0; q < 4; q++) {
      ins(S[q].x, D[q].x, A[q].x, C[q].x);
      ins(S[q].y, D[q].y, A[q].y, C[q].y);
      ins(S[q].z, D[q].z, A[q].z, C[q].z);
      ins(S[q].w, D[q].w, A[q].w, C[q].w);
    }
  } else {
    for (int e = e0; e < E; e++) ins(src[e], dst[e], amount[e], count[e]);
  }
  __syncthreads();
  const int ned = min(CHUNKA, E - blk * CHUNKA);
  for (int i = t; i < ned; i += 256) payload[lgpos[i]] = lpay[i];
}

// ---------- binB: per-bucket fine counting sort -> node-sorted edge_s ----------
// edge_s keeps fine bits: .x = dst | (fine << 20)
__global__ __launch_bounds__(256) void binB_k(const int2* __restrict__ payload,
                                              const int* __restrict__ smat,
                                              int2* __restrict__ edge_s,
                                              int E, int nblkA, int nbkt) {
  __shared__ int fcnt[128];
  __shared__ int fs[128];
  __shared__ int fcur[128];
  const int b = blockIdx.x;
  const int t = threadIdx.x;
  const int base = smat[(size_t)b * nblkA];
  const int end  = (b + 1 < nbkt) ? smat[(size_t)(b + 1) * nblkA] : E;
  if (t < 128) fcnt[t] = 0;
  __syncthreads();
  for (int i = base + t; i < end; i += 256)
    atomicAdd(&fcnt[payload[i].x >> 20], 1);
  __syncthreads();
  if (t < 128) fs[t] = fcnt[t];
  __syncthreads();
  for (int off = 1; off < 128; off <<= 1) {
    int v = 0;
    if (t < 128 && t >= off) v = fs[t - off];
    __syncthreads();
    if (t < 128) fs[t] += v;
    __syncthreads();
  }
  if (t < 128) fcur[t] = base + fs[t] - fcnt[t];
  __syncthreads();
  for (int i = base + t; i < end; i += 256) {
    int2 v = payload[i];
    int pos = atomicAdd(&fcur[v.x >> 20], 1);
    edge_s[pos] = v;   // keep fine bits for node-id recovery in fused_k
  }
}

// ---------- per-node projections: G1 fp32; P = half2(G2, h) ----------
__global__ __launch_bounds__(128) void pre_gemm(const float* __restrict__ h,
                                                const float* __restrict__ fc_w,
                                                const float* __restrict__ fc_b,
                                                float* __restrict__ G1,
                                                __half2* __restrict__ P, int N) {
  __shared__ float hs[NB * FDIM];
  const int t = threadIdx.x;
  const int o = t & 63, half = t >> 6;
  float w[FDIM];
  const float* wrow = fc_w + o * 128 + half * 64;
  #pragma unroll
  for (int f = 0; f < FDIM; f += 4) {
    float4 v = *(const float4*)(wrow + f);
    w[f] = v.x; w[f + 1] = v.y; w[f + 2] = v.z; w[f + 3] = v.w;
  }
  const float bias = (half == 0) ? fc_b[o] : 0.0f;
  const int n0 = blockIdx.x * NB;
  const int nrows = min(NB, N - n0);
  for (int i = t; i < nrows * FDIM; i += 128) hs[i] = h[(size_t)n0 * FDIM + i];
  __syncthreads();
  for (int n = 0; n < nrows; n++) {
    float acc = bias;
    #pragma unroll
    for (int f = 0; f < FDIM; f += 4) {
      float4 hv = *(const float4*)(&hs[n * FDIM + f]);
      acc += hv.x * w[f] + hv.y * w[f + 1] + hv.z * w[f + 2] + hv.w * w[f + 3];
    }
    if (half == 0) {
      G1[(size_t)(n0 + n) * FDIM + o] = acc;
    } else {
      P[(size_t)(n0 + n) * FDIM + o] =
          __halves2half2(__float2half(acc), __float2half(hs[n * FDIM + o]));
    }
  }
}

__device__ __forceinline__ float2 unpack_h2(unsigned u) {
  __half2 v = *(__half2*)&u;
  return make_float2(__low2float(v), __high2float(v));
}

// ---------- fused: segmented edge-centric pass over node-sorted edges ----------
// Each wave owns a contiguous 64-aligned edge range. Register acc per node;
// plain store for wave-interior nodes, atomicAdd only at range boundaries.
__global__ __launch_bounds__(256) void fused_k(const int2* __restrict__ edge_s,
                                               const int* __restrict__ smat,
                                               const float* __restrict__ G1,
                                               const unsigned* __restrict__ P,
                                               double* __restrict__ colsum,
                                               float* __restrict__ out,
                                               int E, int nblkA, int nbkt) {
  const int lane = threadIdx.x & 63;
  const int wv = __builtin_amdgcn_readfirstlane(threadIdx.x >> 6);
  const int wid = blockIdx.x * 4 + wv;
  const int nw = gridDim.x * 4;
  float csum = 0.0f;
  const int per = (((E + nw - 1) / nw) + 63) & ~63;   // 64-aligned range per wave
  const int e0 = wid * per;
  const int e1 = min(e0 + per, E);
  if (e0 < E) {
    // binary search: largest bkt with smat[bkt*nblkA] <= e0
    int lo = 0, hi = nbkt - 1;
    while (lo < hi) {
      int mid = (lo + hi + 1) >> 1;
      if (smat[(size_t)mid * nblkA] <= e0) lo = mid; else hi = mid - 1;
    }
    int bkt = lo;
    int nextb = (bkt + 1 < nbkt) ? smat[(size_t)(bkt + 1) * nblkA] : E;
    int curnode = -1;
    bool firstf = true;
    float acc = 0.0f, g1 = 0.0f;
    auto flush_to = [&](int node) {   // wave-uniform control
      if (curnode >= 0) {
        float* dp = out + (size_t)curnode * FDIM + lane;
        if (firstf) { atomicAdd(dp, acc); firstf = false; }
        else *dp = acc;
      }
      curnode = node; acc = 0.0f;
      g1 = G1[(size_t)node * FDIM + lane];
    };
    for (int c0 = e0; c0 < e1; c0 += 64) {
      const int m = min(64, e1 - c0);
      int2 p = make_int2(0, 0);
      if (lane < m) p = edge_s[c0 + lane];
      if (m == 64) {
        #pragma unroll 1
        for (int j = 0; j < 64; j += 16) {
          int dd[16], nd[16]; float ee[16]; unsigned uu[16];
          #pragma unroll
          for (int k = 0; k < 16; k++) {
            int x = __builtin_amdgcn_readlane(p.x, j + k);
            ee[k] = __int_as_float(__builtin_amdgcn_readlane(p.y, j + k));
            dd[k] = x & DMASK;
            nd[k] = x >> 20;
          }
          #pragma unroll
          for (int k = 0; k < 16; k++) uu[k] = P[(size_t)dd[k] * FDIM + lane];
          #pragma unroll
          for (int k = 0; k < 16; k++) {
            int i = c0 + j + k;
            while (i >= nextb) { bkt++; nextb = (bkt + 1 < nbkt) ? smat[(size_t)(bkt + 1) * nblkA] : E; }
            int node = (bkt << BSHIFT) + nd[k];
            if (node != curnode) flush_to(node);
            float2 v = unpack_h2(uu[k]);
            float sc = g1 + v.x;
            sc = fmaxf(sc, 0.01f * sc);        // leaky_relu
            float x = exp2f(sc * ee[k]);       // log2e folded into ew
            csum += x;
            acc += x * v.y;
          }
        }
      } else {
        for (int j = 0; j < m; j += 16) {
          const int rem = m - j;
          int dd[16], nd[16]; float ee[16]; unsigned uu[16];
          #pragma unroll
          for (int k = 0; k < 16; k++) {
            int x = __builtin_amdgcn_readlane(p.x, j + k);
            ee[k] = __int_as_float(__builtin_amdgcn_readlane(p.y, j + k));
            dd[k] = x & DMASK;
            nd[k] = x >> 20;
          }
          #pragma unroll
          for (int k = 0; k < 16; k++) uu[k] = P[(size_t)dd[k] * FDIM + lane];
          #pragma unroll
          for (int k = 0; k < 16; k++) {
            if (k < rem) {                      // wave-uniform guard
              int i = c0 + j + k;
              while (i >= nextb) { bkt++; nextb = (bkt + 1 < nbkt) ? smat[(size_t)(bkt + 1) * nblkA] : E; }
              int node = (bkt << BSHIFT) + nd[k];
              if (node != curnode) flush_to(node);
              float2 v = unpack_h2(uu[k]);
              float sc = g1 + v.x;
              sc = fmaxf(sc, 0.01f * sc);
              float x = exp2f(sc * ee[k]);
              csum += x;
              acc += x * v.y;
            }
          }
        }
      }
    }
    if (curnode >= 0) atomicAdd(out + (size_t)curnode * FDIM + lane, acc);  // range-end: always atomic
  }
  __shared__ float part[256];
  part[threadIdx.x] = csum;
  __syncthreads();
  if (threadIdx.x < 64) {
    float tot = part[threadIdx.x] + part[threadIdx.x + 64] +
                part[threadIdx.x + 128] + part[threadIdx.x + 192];
    atomicAdd(&colsum[threadIdx.x * 16], (double)tot);   // 128B line per feature
  }
}

// ---------- epilogue: out *= 1/colsum[feature], float4 ----------
__global__ __launch_bounds__(256) void scale_k(float4* __restrict__ out4,
                                               const double* __restrict__ colsum,
                                               int total4) {
  __shared__ float rinv_s[64];
  if (threadIdx.x < 64) rinv_s[threadIdx.x] = (float)(1.0 / colsum[threadIdx.x * 16]);
  __syncthreads();
  const float4* r4 = (const float4*)rinv_s;
  int idx = blockIdx.x * blockDim.x + threadIdx.x;
  int stride = gridDim.x * blockDim.x;
  for (int i = idx; i < total4; i += stride) {
    float4 v = out4[i];
    float4 r = r4[i & 15];
    v.x *= r.x; v.y *= r.y; v.z *= r.z; v.w *= r.w;
    out4[i] = v;
  }
}

extern "C" void kernel_launch(void* const* d_in, const int* in_sizes, int n_in,
                              void* d_out, int out_size, void* d_ws, size_t ws_size,
                              hipStream_t stream) {
  const float* h      = (const float*)d_in[0];
  const int*   adj    = (const int*)d_in[1];
  const float* amount = (const float*)d_in[2];
  const float* count  = (const float*)d_in[3];
  const float* fc_w   = (const float*)d_in[4];
  const float* fc_b   = (const float*)d_in[5];
  float* out = (float*)d_out;

  const int E = in_sizes[2];
  const int N = in_sizes[0] / FDIM;
  const int* src = adj;
  const int* dst = adj + E;
  const int nbkt  = (N + BMASK) >> BSHIFT;           // 128-node buckets (<=1024)
  const int nblkA = (E + CHUNKA - 1) / CHUNKA;
  const int M = nbkt * nblkA;
  const int nchunk = (M + SCH - 1) / SCH;

  // ---- workspace layout (256B-aligned) ----
  char* ws = (char*)d_ws;
  size_t off = 0;
  auto alloc = [&](size_t bytes) { void* p = ws + off; off += (bytes + 255) & ~(size_t)255; return p; };
  float*    G1      = (float*)alloc((size_t)N * FDIM * sizeof(float));
  __half2*  P       = (__half2*)alloc((size_t)N * FDIM * sizeof(__half2));
  int2*     edge_s  = (int2*)alloc((size_t)E * sizeof(int2));
  int2*     payload = (int2*)alloc((size_t)E * sizeof(int2));
  int*      mat     = (int*)alloc((size_t)M * sizeof(int));
  int*      smat    = (int*)alloc((size_t)M * sizeof(int));
  int*      bsum    = (int*)alloc((size_t)nchunk * sizeof(int));
  int*      bexcl   = (int*)alloc((size_t)nchunk * sizeof(int));
  float4*   mmpart  = (float4*)alloc((size_t)nblkA * sizeof(float4));
  double*   colsum  = (double*)alloc(1024 * sizeof(double));   // padded: [f*16]
  float*    mmf     = (float*)alloc(4 * sizeof(float));

  hipMemsetAsync(d_out, 0, (size_t)out_size * sizeof(float), stream);
  count_mm_k<<<nblkA, 256, 0, stream>>>(src, amount, count, mat, mmpart, colsum, E, nblkA, nbkt);
  scan1_k<<<nchunk, 256, 0, stream>>>(mat, bsum, M);
  scan2_k<<<1, 256, 0, stream>>>(bsum, bexcl, nchunk, mmpart, mmf, nblkA);
  scan3_k<<<nchunk, 256, 0, stream>>>(mat, bexcl, smat, M);
  scatter_k<<<nblkA, 256, 0, stream>>>(src, dst, amount, count, mmf, smat, payload, E, nblkA, nbkt);
  binB_k<<<nbkt, 256, 0, stream>>>(payload, smat, edge_s, E, nblkA, nbkt);
  pre_gemm<<<(N + NB - 1) / NB, 128, 0, stream>>>(h, fc_w, fc_b, G1, P, N);
  fused_k<<<4096, 256, 0, stream>>>(edge_s, smat, G1, (const unsigned*)P, colsum, out, E, nblkA, nbkt);
  scale_k<<<1024, 256, 0, stream>>>((float4*)out, colsum, N * FDIM / 4);
}